// Round 1
// baseline (2005.526 us; speedup 1.0000x reference)
//
#include <hip/hip_runtime.h>
#include <cstdint>
#include <cmath>

#define N0G 100000
#define N1G 25000
#define N2G 6250
#define E0G 1600000
#define E1G 400000
#define E2G 100000
#define KCH 6
#define NCLS 40

static inline int cdiv(long a, long b){ return (int)((a + b - 1) / b); }

__device__ __forceinline__ float dinvf(float d){ return d > 0.f ? rsqrtf(d) : 0.f; }

// ---------------- degree + norm ----------------
__global__ void k_deg(const int* __restrict__ row, int E, float* __restrict__ deg){
  int e = blockIdx.x * blockDim.x + threadIdx.x;
  if (e < E) atomicAdd(&deg[row[e]], 1.0f);
}

__global__ void k_norm(const int* __restrict__ row, const int* __restrict__ col,
                       const float* __restrict__ deg, int E, float* __restrict__ nrm){
  int e = blockIdx.x * blockDim.x + threadIdx.x;
  if (e < E){
    float a = deg[row[e]], b = deg[col[e]];
    nrm[e] = -(dinvf(a) * dinvf(b));
  }
}

__global__ void k_negcopy(const float* __restrict__ s, float* __restrict__ d, int n){
  int i = blockIdx.x * blockDim.x + threadIdx.x;
  if (i < n) d[i] = -s[i];
}

// ---------------- Lhat scatter (edge) kernels ----------------
__global__ void k_lhat3(const int* __restrict__ row, const int* __restrict__ col,
                        const float* __restrict__ nrm, const float* __restrict__ src,
                        float* __restrict__ dst, int E, float scale){
  int e = blockIdx.x * blockDim.x + threadIdx.x;
  if (e >= E) return;
  float w = scale * nrm[e];
  int c = col[e] * 3, r = row[e] * 3;
  atomicAdd(&dst[r + 0], w * src[c + 0]);
  atomicAdd(&dst[r + 1], w * src[c + 1]);
  atomicAdd(&dst[r + 2], w * src[c + 2]);
}

template<int F>
__global__ void k_lhatF(const int* __restrict__ row, const int* __restrict__ col,
                        const float* __restrict__ nrm, const float* __restrict__ src,
                        float* __restrict__ dst, int E, float scale){
  int t = blockIdx.x * blockDim.x + threadIdx.x;
  int e = t / F, f = t % F;            // F is power of 2 -> shifts
  if (e >= E) return;
  float w = scale * nrm[e];
  atomicAdd(&dst[(long)row[e] * F + f], w * src[(long)col[e] * F + f]);
}

// ---------------- dense cheb contraction: out[n,o] = b[o] + sum_{k,f} T[k][n][f] * W[k][f][o] ----------------
template<int F, int FO, bool RELU>
__global__ void k_cheb_out(const float* __restrict__ T, int N,
                           const float* __restrict__ W, const float* __restrict__ b,
                           float* __restrict__ out){
  long t = (long)blockIdx.x * blockDim.x + threadIdx.x;
  int n = (int)(t / FO), o = (int)(t % FO);
  if (n >= N) return;
  float acc = b[o];
  for (int k = 0; k < KCH; k++){
    const float* Tk = T + ((long)k * N + n) * F;
    const float* Wk = W + (long)(k * F) * FO + o;
    for (int f = 0; f < F; f++)
      acc = fmaf(Tk[f], Wk[(long)f * FO], acc);
  }
  out[(long)n * FO + o] = RELU ? fmaxf(acc, 0.f) : acc;
}

// ---------------- pooling scatter ----------------
template<int F>
__global__ void k_pool(const int* __restrict__ row, const int* __restrict__ col,
                       const float* __restrict__ val, const float* __restrict__ h,
                       float* __restrict__ out, int E){
  int t = blockIdx.x * blockDim.x + threadIdx.x;
  int e = t / F, f = t % F;
  if (e >= E) return;
  atomicAdd(&out[(long)row[e] * F + f], val[e] * h[(long)col[e] * F + f]);
}

// ---------------- final hidden GEMM + global max + classifier ----------------
__device__ __forceinline__ unsigned fmap(float x){
  unsigned u = __float_as_uint(x);
  return (u & 0x80000000u) ? ~u : (u | 0x80000000u);
}
__device__ __forceinline__ float funmap(unsigned u){
  return (u & 0x80000000u) ? __uint_as_float(u ^ 0x80000000u) : __uint_as_float(~u);
}

__global__ void k_init_max(unsigned* __restrict__ m){
  m[blockIdx.x * blockDim.x + threadIdx.x] = fmap(-INFINITY);
}

#define NB 25
__global__ void k_hidden_max(const float* __restrict__ h2, const float* __restrict__ Wh,
                             const float* __restrict__ bh, unsigned* __restrict__ maxed, int N){
  __shared__ float sh[NB * 128];
  int o  = blockIdx.x * 256 + threadIdx.x;   // 4 o-tiles of 256
  int n0 = blockIdx.y * NB;                  // 250 node chunks of 25
  for (int i = threadIdx.x; i < NB * 128; i += 256){
    int n = n0 + i / 128;
    sh[i] = (n < N) ? h2[(long)n * 128 + (i & 127)] : 0.f;
  }
  __syncthreads();
  float acc[NB];
#pragma unroll
  for (int n = 0; n < NB; n++) acc[n] = 0.f;
  for (int f = 0; f < 128; f++){
    float w = Wh[(long)f * 1024 + o];
#pragma unroll
    for (int n = 0; n < NB; n++) acc[n] = fmaf(sh[n * 128 + f], w, acc[n]);
  }
  float bo = bh[o];
  float m = -INFINITY;
#pragma unroll
  for (int n = 0; n < NB; n++)
    if (n0 + n < N) m = fmaxf(m, acc[n] + bo);
  atomicMax(&maxed[o], fmap(m));
}

__global__ void k_final(const unsigned* __restrict__ maxed, const float* __restrict__ Wl,
                        const float* __restrict__ bl, float* __restrict__ out){
  int c = threadIdx.x;
  if (c >= NCLS) return;
  float acc = bl[c];
  for (int o = 0; o < 1024; o++)
    acc = fmaf(funmap(maxed[o]), Wl[o * NCLS + c], acc);
  out[c] = acc;
}

// ---------------- per-layer cheb driver ----------------
template<int F, int FO, bool RELU>
static void run_cheb(const int* row, const int* col, int E, int N,
                     const float* x, const float* W, const float* b, float* out,
                     float* nrm, float* deg, float* T, hipStream_t s){
  const int B = 256;
  hipMemsetAsync(deg, 0, (size_t)N * sizeof(float), s);
  k_deg<<<cdiv(E, B), B, 0, s>>>(row, E, deg);
  k_norm<<<cdiv(E, B), B, 0, s>>>(row, col, deg, E, nrm);
  // T0 = x
  hipMemcpyAsync(T, x, (size_t)N * F * sizeof(float), hipMemcpyDeviceToDevice, s);
  // T1 = Lhat(T0)
  hipMemsetAsync(T + (size_t)N * F, 0, (size_t)N * F * sizeof(float), s);
  if constexpr (F == 3)
    k_lhat3<<<cdiv(E, B), B, 0, s>>>(row, col, nrm, T, T + (size_t)N * F, E, 1.0f);
  else
    k_lhatF<F><<<cdiv((long)E * F, B), B, 0, s>>>(row, col, nrm, T, T + (size_t)N * F, E, 1.0f);
  // Tk = 2*Lhat(T_{k-1}) - T_{k-2}
  for (int k = 2; k < KCH; k++){
    float* Tk  = T + (size_t)k * N * F;
    float* Tm1 = T + (size_t)(k - 1) * N * F;
    float* Tm2 = T + (size_t)(k - 2) * N * F;
    k_negcopy<<<cdiv((long)N * F, B), B, 0, s>>>(Tm2, Tk, N * F);
    if constexpr (F == 3)
      k_lhat3<<<cdiv(E, B), B, 0, s>>>(row, col, nrm, Tm1, Tk, E, 2.0f);
    else
      k_lhatF<F><<<cdiv((long)E * F, B), B, 0, s>>>(row, col, nrm, Tm1, Tk, E, 2.0f);
  }
  k_cheb_out<F, FO, RELU><<<cdiv((long)N * FO, B), B, 0, s>>>(T, N, W, b, out);
}

extern "C" void kernel_launch(void* const* d_in, const int* in_sizes, int n_in,
                              void* d_out, int out_size, void* d_ws, size_t ws_size,
                              hipStream_t stream){
  const float* pos = (const float*)d_in[0];
  const int*   ei0 = (const int*)d_in[1];
  const int*   ei1 = (const int*)d_in[2];
  const int*   ei2 = (const int*)d_in[3];
  const int*   p0r = (const int*)d_in[4];
  const int*   p0c = (const int*)d_in[5];
  const float* p0v = (const float*)d_in[6];
  const int*   p1r = (const int*)d_in[7];
  const int*   p1c = (const int*)d_in[8];
  const float* p1v = (const float*)d_in[9];
  const float* W0  = (const float*)d_in[10]; const float* b0 = (const float*)d_in[11];
  const float* W1  = (const float*)d_in[12]; const float* b1 = (const float*)d_in[13];
  const float* W2  = (const float*)d_in[14]; const float* b2 = (const float*)d_in[15];
  const float* Wh  = (const float*)d_in[16]; const float* bh = (const float*)d_in[17];
  const float* Wl  = (const float*)d_in[18]; const float* bl = (const float*)d_in[19];
  float* out = (float*)d_out;

  // workspace layout (floats)
  float* base = (float*)d_ws;
  float* nrm  = base;                       // E0 max       (1.6M)
  float* deg  = nrm + E0G;                  // N0 max       (100K)
  float* Tbuf = deg + N0G;                  // 6*N1*32 max  (4.8M)
  float* hA   = Tbuf + 4800000;             // N0*32        (3.2M)
  float* hB   = hA + (long)N0G * 32;        // N1*64 / N2*128 (1.6M)
  float* hC   = hB + 1600000;               // N1*32 / N2*64  (800K)
  unsigned* maxed = (unsigned*)(hC + 800000);

  const int B = 256;

  // layer 0: cheb(pos) -> hA [N0,32], relu
  run_cheb<3, 32, true>(ei0, ei0 + E0G, E0G, N0G, pos, W0, b0, hA, nrm, deg, Tbuf, stream);

  // pool 0: hA -> hC [N1,32]
  hipMemsetAsync(hC, 0, (size_t)N1G * 32 * sizeof(float), stream);
  k_pool<32><<<cdiv((long)N0G * 32, B), B, 0, stream>>>(p0r, p0c, p0v, hA, hC, N0G);

  // layer 1: cheb(hC) -> hB [N1,64], relu
  run_cheb<32, 64, true>(ei1, ei1 + E1G, E1G, N1G, hC, W1, b1, hB, nrm, deg, Tbuf, stream);

  // pool 1: hB -> hC [N2,64]
  hipMemsetAsync(hC, 0, (size_t)N2G * 64 * sizeof(float), stream);
  k_pool<64><<<cdiv((long)N1G * 64, B), B, 0, stream>>>(p1r, p1c, p1v, hB, hC, N1G);

  // layer 2: cheb(hC) -> hB [N2,128], no relu
  run_cheb<64, 128, false>(ei2, ei2 + E2G, E2G, N2G, hC, W2, b2, hB, nrm, deg, Tbuf, stream);

  // hidden GEMM + global max over nodes
  k_init_max<<<4, 256, 0, stream>>>(maxed);
  dim3 g(4, 250);
  k_hidden_max<<<g, 256, 0, stream>>>(hB, Wh, bh, maxed, N2G);

  // classifier
  k_final<<<1, 64, 0, stream>>>(maxed, Wl, bl, out);
}

// Round 2
// 937.868 us; speedup vs baseline: 2.1384x; 2.1384x over previous
//
#include <hip/hip_runtime.h>
#include <cstdint>
#include <cmath>

#define N0G 100000
#define N1G 25000
#define N2G 6250
#define E0G 1600000
#define E1G 400000
#define E2G 100000
#define KCH 6
#define NCLS 40

static inline int cdiv(long a, long b){ return (int)((a + b - 1) / b); }

// ---------------- CSR build: histogram, scan, scatter ----------------
__global__ void k_hist(const int* __restrict__ row, int E, int* __restrict__ deg){
  int e = blockIdx.x * blockDim.x + threadIdx.x;
  if (e < E) atomicAdd(&deg[row[e]], 1);
}

__global__ void k_chunk_sums(const int* __restrict__ deg, int N, int* __restrict__ bsum){
  __shared__ int sh[256];
  int base = blockIdx.x * 1024 + threadIdx.x * 4;
  int s = 0;
  for (int j = 0; j < 4; j++){ int i = base + j; if (i < N) s += deg[i]; }
  sh[threadIdx.x] = s; __syncthreads();
  for (int o = 128; o > 0; o >>= 1){
    if (threadIdx.x < o) sh[threadIdx.x] += sh[threadIdx.x + o];
    __syncthreads();
  }
  if (threadIdx.x == 0) bsum[blockIdx.x] = sh[0];
}

__global__ void k_scan_bsum(int* __restrict__ bsum, int nb){
  if (threadIdx.x == 0){
    int acc = 0;
    for (int i = 0; i < nb; i++){ int v = bsum[i]; bsum[i] = acc; acc += v; }
  }
}

__global__ void k_scan_write(const int* __restrict__ deg, int N,
                             const int* __restrict__ bsum, int* __restrict__ rp, int E){
  __shared__ int sh[256];
  int base = blockIdx.x * 1024 + threadIdx.x * 4;
  int v[4]; int s = 0;
  for (int j = 0; j < 4; j++){ int i = base + j; v[j] = (i < N) ? deg[i] : 0; s += v[j]; }
  sh[threadIdx.x] = s; __syncthreads();
  for (int o = 1; o < 256; o <<= 1){
    int t = (threadIdx.x >= o) ? sh[threadIdx.x - o] : 0;
    __syncthreads();
    sh[threadIdx.x] += t;
    __syncthreads();
  }
  int excl = bsum[blockIdx.x] + sh[threadIdx.x] - s;
  for (int j = 0; j < 4; j++){ int i = base + j; if (i < N){ rp[i] = excl; excl += v[j]; } }
  if (blockIdx.x == 0 && threadIdx.x == 0) rp[N] = E;
}

__global__ void k_dinv(const int* __restrict__ deg, int N, float* __restrict__ dinv){
  int n = blockIdx.x * blockDim.x + threadIdx.x;
  if (n < N){ int d = deg[n]; dinv[n] = d > 0 ? rsqrtf((float)d) : 0.f; }
}

// graph scatter: CSR col + weight dinv[col]
__global__ void k_scatter_g(const int* __restrict__ row, const int* __restrict__ col,
                            const float* __restrict__ dinv, int E,
                            int* __restrict__ cursor, int* __restrict__ cs, float* __restrict__ wv){
  int e = blockIdx.x * blockDim.x + threadIdx.x;
  if (e < E){
    int p = atomicAdd(&cursor[row[e]], 1);
    int c = col[e];
    cs[p] = c; wv[p] = dinv[c];
  }
}

// pool scatter: CSR col + given value
__global__ void k_scatter_p(const int* __restrict__ row, const int* __restrict__ col,
                            const float* __restrict__ val, int E,
                            int* __restrict__ cursor, int* __restrict__ cs, float* __restrict__ wv){
  int e = blockIdx.x * blockDim.x + threadIdx.x;
  if (e < E){
    int p = atomicAdd(&cursor[row[e]], 1);
    cs[p] = col[e]; wv[p] = val[e];
  }
}

// ---------------- CSR gather SpMM ----------------
// dst[n,:] = (GRAPH ? -scale*dinv[n]*sum_e wv*src[cs] - sub[n,:]
//                   :  sum_e wv*src[cs])
__global__ void k_gather3(const int* __restrict__ rp, const int* __restrict__ cs,
                          const float* __restrict__ wv, const float* __restrict__ src,
                          const float* __restrict__ dinv, const float* __restrict__ sub,
                          float* __restrict__ dst, int N, float scale){
  int n = blockIdx.x * blockDim.x + threadIdx.x;
  if (n >= N) return;
  int e0 = rp[n], e1 = rp[n + 1];
  float a0 = 0.f, a1 = 0.f, a2 = 0.f;
  for (int e = e0; e < e1; e++){
    int c = cs[e] * 3; float w = wv[e];
    a0 = fmaf(w, src[c + 0], a0);
    a1 = fmaf(w, src[c + 1], a1);
    a2 = fmaf(w, src[c + 2], a2);
  }
  float m = -scale * dinv[n];
  float r0 = m * a0, r1 = m * a1, r2 = m * a2;
  if (sub){ r0 -= sub[n * 3 + 0]; r1 -= sub[n * 3 + 1]; r2 -= sub[n * 3 + 2]; }
  dst[n * 3 + 0] = r0; dst[n * 3 + 1] = r1; dst[n * 3 + 2] = r2;
}

template<int F, bool GRAPH>
__global__ void k_gather(const int* __restrict__ rp, const int* __restrict__ cs,
                         const float* __restrict__ wv, const float* __restrict__ src,
                         const float* __restrict__ dinv, const float* __restrict__ sub,
                         float* __restrict__ dst, int N, float scale){
  int n = blockIdx.x * (256 / F) + threadIdx.x / F;
  int f = threadIdx.x % F;
  if (n >= N) return;
  int e0 = rp[n], e1 = rp[n + 1];
  float acc = 0.f;
  for (int e = e0; e < e1; e++){
    int c = cs[e];
    acc = fmaf(wv[e], src[(long)c * F + f], acc);
  }
  float r;
  if (GRAPH){
    r = -scale * dinv[n] * acc;
    if (sub) r -= sub[(long)n * F + f];
  } else {
    r = acc;
  }
  dst[(long)n * F + f] = r;
}

// ---------------- dense cheb contraction ----------------
// out[n,o] = b[o] + sum_f x[n,f]*W[0][f,o] + sum_{k=1..5,f} T[k-1][n,f]*W[k][f,o]
template<int F, int FO, bool RELU>
__global__ void k_cheb_out(const float* __restrict__ x, const float* __restrict__ T, int N,
                           const float* __restrict__ W, const float* __restrict__ b,
                           float* __restrict__ out){
  long t = (long)blockIdx.x * blockDim.x + threadIdx.x;
  int n = (int)(t / FO), o = (int)(t % FO);
  if (n >= N) return;
  float acc = b[o];
  const float* xr = x + (long)n * F;
  const float* W0 = W + o;
  for (int f = 0; f < F; f++)
    acc = fmaf(xr[f], W0[(long)f * FO], acc);
  for (int k = 1; k < KCH; k++){
    const float* Tk = T + ((long)(k - 1) * N + n) * F;
    const float* Wk = W + (long)k * F * FO + o;
    for (int f = 0; f < F; f++)
      acc = fmaf(Tk[f], Wk[(long)f * FO], acc);
  }
  out[(long)n * FO + o] = RELU ? fmaxf(acc, 0.f) : acc;
}

// ---------------- final hidden GEMM + global max + classifier ----------------
__device__ __forceinline__ unsigned fmap(float x){
  unsigned u = __float_as_uint(x);
  return (u & 0x80000000u) ? ~u : (u | 0x80000000u);
}
__device__ __forceinline__ float funmap(unsigned u){
  return (u & 0x80000000u) ? __uint_as_float(u ^ 0x80000000u) : __uint_as_float(~u);
}

__global__ void k_init_max(unsigned* __restrict__ m){
  m[blockIdx.x * blockDim.x + threadIdx.x] = fmap(-INFINITY);
}

#define NB 25
__global__ void k_hidden_max(const float* __restrict__ h2, const float* __restrict__ Wh,
                             const float* __restrict__ bh, unsigned* __restrict__ maxed, int N){
  __shared__ float sh[NB * 128];
  int o  = blockIdx.x * 256 + threadIdx.x;
  int n0 = blockIdx.y * NB;
  for (int i = threadIdx.x; i < NB * 128; i += 256){
    int n = n0 + i / 128;
    sh[i] = (n < N) ? h2[(long)n * 128 + (i & 127)] : 0.f;
  }
  __syncthreads();
  float acc[NB];
#pragma unroll
  for (int n = 0; n < NB; n++) acc[n] = 0.f;
  for (int f = 0; f < 128; f++){
    float w = Wh[(long)f * 1024 + o];
#pragma unroll
    for (int n = 0; n < NB; n++) acc[n] = fmaf(sh[n * 128 + f], w, acc[n]);
  }
  float bo = bh[o];
  float m = -INFINITY;
#pragma unroll
  for (int n = 0; n < NB; n++)
    if (n0 + n < N) m = fmaxf(m, acc[n] + bo);
  atomicMax(&maxed[o], fmap(m));
}

__global__ void k_final(const unsigned* __restrict__ maxed, const float* __restrict__ Wl,
                        const float* __restrict__ bl, float* __restrict__ out){
  int c = threadIdx.x;
  if (c >= NCLS) return;
  float acc = bl[c];
  for (int o = 0; o < 1024; o++)
    acc = fmaf(funmap(maxed[o]), Wl[o * NCLS + c], acc);
  out[c] = acc;
}

// ---------------- drivers ----------------
static void build_csr_common(const int* row, int E, int N,
                             int* deg, int* bsum, int* rp, int* cursor, hipStream_t s){
  const int B = 256;
  hipMemsetAsync(deg, 0, (size_t)N * sizeof(int), s);
  k_hist<<<cdiv(E, B), B, 0, s>>>(row, E, deg);
  int nb = cdiv(N, 1024);
  k_chunk_sums<<<nb, 256, 0, s>>>(deg, N, bsum);
  k_scan_bsum<<<1, 64, 0, s>>>(bsum, nb);
  k_scan_write<<<nb, 256, 0, s>>>(deg, N, bsum, rp, E);
  hipMemcpyAsync(cursor, rp, (size_t)N * sizeof(int), hipMemcpyDeviceToDevice, s);
}

template<int F, int FO, bool RELU>
static void run_cheb(const int* row, const int* col, int E, int N,
                     const float* x, const float* W, const float* b, float* out,
                     float* T, int* csr_col, float* csr_w,
                     int* rp, int* cursor, int* deg, float* dinv, int* bsum,
                     hipStream_t s){
  const int B = 256;
  build_csr_common(row, E, N, deg, bsum, rp, cursor, s);
  k_dinv<<<cdiv(N, B), B, 0, s>>>(deg, N, dinv);
  k_scatter_g<<<cdiv(E, B), B, 0, s>>>(row, col, dinv, E, cursor, csr_col, csr_w);

  const float* src = x; const float* sub = nullptr; float scale = 1.f;
  for (int k = 1; k < KCH; k++){
    float* Tk = T + (size_t)(k - 1) * N * F;
    if constexpr (F == 3)
      k_gather3<<<cdiv(N, B), B, 0, s>>>(rp, csr_col, csr_w, src, dinv, sub, Tk, N, scale);
    else
      k_gather<F, true><<<cdiv(N, 256 / F), 256, 0, s>>>(rp, csr_col, csr_w, src, dinv, sub, Tk, N, scale);
    sub = src; src = Tk; scale = 2.f;
  }
  k_cheb_out<F, FO, RELU><<<cdiv((long)N * FO, B), B, 0, s>>>(x, T, N, W, b, out);
}

template<int F>
static void run_pool(const int* row, const int* col, const float* val, int E, int Nout,
                     const float* h, float* out, int* csr_col, float* csr_w,
                     int* rp, int* cursor, int* deg, int* bsum, hipStream_t s){
  const int B = 256;
  build_csr_common(row, E, Nout, deg, bsum, rp, cursor, s);
  k_scatter_p<<<cdiv(E, B), B, 0, s>>>(row, col, val, E, cursor, csr_col, csr_w);
  k_gather<F, false><<<cdiv(Nout, 256 / F), 256, 0, s>>>(rp, csr_col, csr_w, h, nullptr, nullptr, out, Nout, 1.f);
}

extern "C" void kernel_launch(void* const* d_in, const int* in_sizes, int n_in,
                              void* d_out, int out_size, void* d_ws, size_t ws_size,
                              hipStream_t stream){
  const float* pos = (const float*)d_in[0];
  const int*   ei0 = (const int*)d_in[1];
  const int*   ei1 = (const int*)d_in[2];
  const int*   ei2 = (const int*)d_in[3];
  const int*   p0r = (const int*)d_in[4];
  const int*   p0c = (const int*)d_in[5];
  const float* p0v = (const float*)d_in[6];
  const int*   p1r = (const int*)d_in[7];
  const int*   p1c = (const int*)d_in[8];
  const float* p1v = (const float*)d_in[9];
  const float* W0  = (const float*)d_in[10]; const float* b0 = (const float*)d_in[11];
  const float* W1  = (const float*)d_in[12]; const float* b1 = (const float*)d_in[13];
  const float* W2  = (const float*)d_in[14]; const float* b2 = (const float*)d_in[15];
  const float* Wh  = (const float*)d_in[16]; const float* bh = (const float*)d_in[17];
  const float* Wl  = (const float*)d_in[18]; const float* bl = (const float*)d_in[19];
  float* out = (float*)d_out;

  // workspace layout (floats). R holds T(5 slots) + per-stage CSR col/w.
  float* R  = (float*)d_ws;                 // 4.8M floats
  float* hA = R + 4800000;                  // N0*32 = 3.2M
  float* hB = hA + 3200000;                 // 1.6M (N1*64 / N2*128)
  float* hC = hB + 1600000;                 // 0.8M (N1*32 / N2*64)
  int* rp     = (int*)(hC + 800000);        // 100001
  int* cursor = rp + 100001;                // 100000
  int* deg    = cursor + 100000;            // 100000
  float* dinv = (float*)(deg + 100000);     // 100000
  int* bsum   = (int*)(dinv + 100000);      // 256
  unsigned* maxed = (unsigned*)(bsum + 256);// 1024

  // layer 0: cheb(pos) -> hA [N0,32], relu. T=5*N0*3=1.5M
  run_cheb<3, 32, true>(ei0, ei0 + E0G, E0G, N0G, pos, W0, b0, hA,
                        R, (int*)(R + 1500000), R + 3100000,
                        rp, cursor, deg, dinv, bsum, stream);

  // pool 0: hA -> hC [N1,32]
  run_pool<32>(p0r, p0c, p0v, N0G, N1G, hA, hC,
               (int*)R, R + 100000, rp, cursor, deg, bsum, stream);

  // layer 1: cheb(hC) -> hB [N1,64], relu. T=5*N1*32=4.0M
  run_cheb<32, 64, true>(ei1, ei1 + E1G, E1G, N1G, hC, W1, b1, hB,
                         R, (int*)(R + 4000000), R + 4400000,
                         rp, cursor, deg, dinv, bsum, stream);

  // pool 1: hB -> hC [N2,64]
  run_pool<64>(p1r, p1c, p1v, N1G, N2G, hB, hC,
               (int*)R, R + 100000, rp, cursor, deg, bsum, stream);

  // layer 2: cheb(hC) -> hB [N2,128], no relu. T=5*N2*64=2.0M
  run_cheb<64, 128, false>(ei2, ei2 + E2G, E2G, N2G, hC, W2, b2, hB,
                           R, (int*)(R + 2000000), R + 2100000,
                           rp, cursor, deg, dinv, bsum, stream);

  // hidden GEMM + global max over nodes
  k_init_max<<<4, 256, 0, stream>>>(maxed);
  dim3 g(4, 250);
  k_hidden_max<<<g, 256, 0, stream>>>(hB, Wh, bh, maxed, N2G);

  // classifier
  k_final<<<1, 64, 0, stream>>>(maxed, Wl, bl, out);
}